// Round 3
// baseline (853.633 us; speedup 1.0000x reference)
//
#include <hip/hip_runtime.h>
#include <stdint.h>

// Problem constants
#define BB 128
#define SS 256
#define EE 1024
#define HH 16
#define DD 64
#define MM (BB*SS)   // 32768

#define LOG2E 1.44269504088896f

typedef __attribute__((ext_vector_type(8))) short bf16x8;
typedef __attribute__((ext_vector_type(4))) float f32x4;

__device__ __forceinline__ unsigned short f2bf(float f) {
  union { float f; unsigned int u; } c; c.f = f;
  unsigned int u = c.u;
  u += 0x7fffu + ((u >> 16) & 1u);   // round-to-nearest-even
  return (unsigned short)(u >> 16);
}

__device__ __forceinline__ float fast_exp2(float x) { return exp2f(x); }
__device__ __forceinline__ float fast_rcp(float x) { return 1.0f / x; }

__device__ __forceinline__ void gld16(const unsigned short* g, unsigned short* l) {
  // async global->LDS, 16B/lane; LDS dest = wave-uniform base + lane*16
  __builtin_amdgcn_global_load_lds((__attribute__((address_space(1))) void*)(g),
                                   (__attribute__((address_space(3))) void*)(l), 16, 0, 0);
}

// ---------------- merged prep: casts + bias matrix [h][q][k] * log2(e) ----------------
__global__ __launch_bounds__(256) void prep_kernel(const float4* __restrict__ x4,
                                                   const float4* __restrict__ qw,
                                                   const float4* __restrict__ ow,
                                                   const float* __restrict__ btab,
                                                   const int* __restrict__ ridx,
                                                   ushort4* __restrict__ xb,
                                                   ushort4* __restrict__ qwb,
                                                   ushort4* __restrict__ owb,
                                                   float* __restrict__ biasm) {
  const int NX = (MM * EE) / 4;       // 8388608 float4
  const int NQ = (3 * EE * EE) / 4;   // 786432 float4
  const int NO = (EE * EE) / 4;       // 262144 float4
  const int NBIAS = HH * SS * SS;     // 1048576 floats
  const int total = NX + NQ + NO + NBIAS;   // 10485760
  int stride = gridDim.x * blockDim.x;
  for (int i = blockIdx.x * blockDim.x + threadIdx.x; i < total; i += stride) {
    if (i < NX) {
      float4 v = x4[i];
      ushort4 r; r.x = f2bf(v.x); r.y = f2bf(v.y); r.z = f2bf(v.z); r.w = f2bf(v.w);
      xb[i] = r;
    } else if (i < NX + NQ) {
      int t = i - NX;
      float4 v = qw[t];
      ushort4 r; r.x = f2bf(v.x); r.y = f2bf(v.y); r.z = f2bf(v.z); r.w = f2bf(v.w);
      qwb[t] = r;
    } else if (i < NX + NQ + NO) {
      int t = i - (NX + NQ);
      float4 v = ow[t];
      ushort4 r; r.x = f2bf(v.x); r.y = f2bf(v.y); r.z = f2bf(v.z); r.w = f2bf(v.w);
      owb[t] = r;
    } else {
      int t = i - (NX + NQ + NO);
      int h = t >> 16;          // [h][q][k], consecutive t = consecutive k (coalesced)
      int qk = t & 65535;
      biasm[t] = btab[ridx[qk] * HH + h] * LOG2E;
    }
  }
}

// ---------------- shared GEMM main loop: C[128,128] += A[M,K] * B[N,K]^T ----------------
// BK=64 (two 32-k substeps per barrier pair) — halves barrier count vs R2.
// LDS rows 128B = 8 x 16B chunks, chunk XOR-swizzled by row&7 (global-side
// inversion keeps the global_load_lds dest contiguous). 32KB total.
__device__ __forceinline__ void gemm_mainloop(const unsigned short* __restrict__ A,
                                              const unsigned short* __restrict__ Bw,
                                              unsigned short* As, unsigned short* Bs,
                                              int row0, int col0, int K,
                                              f32x4 acc[4][4]) {
  const int tid = threadIdx.x;
  const int wave = tid >> 6, lane = tid & 63;
  const int wm = wave & 1, wn = wave >> 1;
  const int l15 = lane & 15, quad = lane >> 4;
  const int swl = l15 & 7;
  const unsigned short* ap[4];
  const unsigned short* bp[4];
#pragma unroll
  for (int p = 0; p < 4; ++p) {
    int slot = p * 256 + tid;
    int srow = slot >> 3;
    int sgc = ((slot & 7) ^ (srow & 7)) * 8;   // swizzle-inverted global chunk
    ap[p] = A + (size_t)(row0 + srow) * K + sgc;
    bp[p] = Bw + (size_t)(col0 + srow) * K + sgc;
  }
  for (int k0 = 0; k0 < K; k0 += 64) {
#pragma unroll
    for (int p = 0; p < 4; ++p) {
      gld16(ap[p] + k0, As + (p * 256 + wave * 64) * 8);
      gld16(bp[p] + k0, Bs + (p * 256 + wave * 64) * 8);
    }
    __syncthreads();   // drains vmcnt (global_load_lds) before LDS reads
#pragma unroll
    for (int ks = 0; ks < 2; ++ks) {
      bf16x8 af[4], bfm[4];
#pragma unroll
      for (int i = 0; i < 4; ++i)
        af[i] = *(const bf16x8*)(As + (wm * 64 + i * 16 + l15) * 64 +
                                 (((ks * 4 + quad) ^ swl)) * 8);
#pragma unroll
      for (int j = 0; j < 4; ++j)
        bfm[j] = *(const bf16x8*)(Bs + (wn * 64 + j * 16 + l15) * 64 +
                                  (((ks * 4 + quad) ^ swl)) * 8);
#pragma unroll
      for (int i = 0; i < 4; ++i)
#pragma unroll
        for (int j = 0; j < 4; ++j)
          acc[i][j] = __builtin_amdgcn_mfma_f32_16x16x32_bf16(af[i], bfm[j], acc[i][j], 0, 0, 0);
    }
    __syncthreads();
  }
}

// ---------------- QKV GEMM: x_bf16 @ qkv_w^T + qkv_b -> q,k (B,H,S,D) / v^T (B,H,D,S) ----------------
__global__ __launch_bounds__(256) void qkv_gemm(const unsigned short* __restrict__ A,
                                                const unsigned short* __restrict__ Bw,
                                                const float* __restrict__ bias,
                                                unsigned short* __restrict__ q,
                                                unsigned short* __restrict__ kx,
                                                unsigned short* __restrict__ vt) {
  __shared__ unsigned short As[128 * 64];
  __shared__ unsigned short Bs[128 * 64];
  const int tid = threadIdx.x;
  const int wave = tid >> 6, lane = tid & 63;
  const int wm = wave & 1, wn = wave >> 1;
  const int l15 = lane & 15, quad = lane >> 4;
  const int row0 = blockIdx.x * 128;
  const int col0 = blockIdx.y * 128;
  f32x4 acc[4][4];
#pragma unroll
  for (int i = 0; i < 4; ++i)
#pragma unroll
    for (int j = 0; j < 4; ++j) acc[i][j] = (f32x4){0.f, 0.f, 0.f, 0.f};
  gemm_mainloop(A, Bw, As, Bs, row0, col0, EE, acc);
  const int which = col0 >> 10;  // block-uniform: 0=q 1=k 2=v
  const float QS = 0.125f * LOG2E;   // fold 1/sqrt(D) and the exp2 domain scale into q
#pragma unroll
  for (int i = 0; i < 4; ++i) {
    const int mbase = row0 + wm * 64 + i * 16 + quad * 4;   // C row = quad*4+reg
    const int bb = mbase >> 8;
    const int s0 = mbase & 255;   // +r stays in-window (no wrap)
#pragma unroll
    for (int j = 0; j < 4; ++j) {
      const int n = col0 + wn * 64 + j * 16 + l15;          // C col = lane&15
      const int hn = (n >> 6) & 15;
      const int d = n & 63;
      const float bv = bias[n];
      if (which == 0) {
        size_t base = ((size_t)(bb * HH + hn) * SS + s0) * DD + d;
#pragma unroll
        for (int r = 0; r < 4; ++r)
          q[base + (size_t)r * DD] = f2bf((acc[i][j][r] + bv) * QS);
      } else if (which == 1) {
        size_t base = ((size_t)(bb * HH + hn) * SS + s0) * DD + d;
#pragma unroll
        for (int r = 0; r < 4; ++r)
          kx[base + (size_t)r * DD] = f2bf(acc[i][j][r] + bv);
      } else {
        size_t base = ((size_t)(bb * HH + hn) * DD + d) * SS + s0;  // transposed v
        ushort4 pk;
        pk.x = f2bf(acc[i][j][0] + bv);
        pk.y = f2bf(acc[i][j][1] + bv);
        pk.z = f2bf(acc[i][j][2] + bv);
        pk.w = f2bf(acc[i][j][3] + bv);
        *(ushort4*)(vt + base) = pk;
      }
    }
  }
}

// ---------------- attention: one block per (b,h); S^T trick, no P LDS ----------------
// S^T = mfma(K-frag, Q-frag): C-layout lane = q-row, so softmax sum = 2 shfl_xor
// and the P->A-frag transform is an exchange among the 4 same-l15 lanes
// (8 shfl + 4 selects per kk). K and V both LDS-resident (64KB). Normalization
// deferred to the ctx epilogue.
__global__ __launch_bounds__(256) void attn_kernel(const unsigned short* __restrict__ q,
                                                   const unsigned short* __restrict__ kx,
                                                   const unsigned short* __restrict__ vt,
                                                   const float* __restrict__ biasm,
                                                   unsigned short* __restrict__ ctx) {
  __shared__ unsigned short Ks[256 * 64];   // 32KB; row=k idx (128B), chunk c at c^(row&7)
  __shared__ unsigned short Vs[64 * 256];   // 32KB; row=d (512B), low-3 chunk bits swizzled
  const int tid = threadIdx.x;
  const int wave = tid >> 6, lane = tid & 63;
  const int l15 = lane & 15, quad = lane >> 4;
  const int swl = l15 & 7;
  const int bh = blockIdx.x;
  const int h = bh & 15;
  const int b_ = bh >> 4;
  const unsigned short* qp = q + (size_t)bh * SS * DD;
  const unsigned short* kp = kx + (size_t)bh * SS * DD;
  const unsigned short* vp = vt + (size_t)bh * DD * SS;

  // stage K: 8 passes x 256 lanes x 16B
#pragma unroll
  for (int rr = 0; rr < 8; ++rr) {
    int gc = rr * 256 + tid;
    int row = gc >> 3, sc = gc & 7;
    int c = sc ^ (row & 7);
    gld16(kp + row * 64 + c * 8, Ks + (rr * 256 + wave * 64) * 8);
  }
  // stage V (row = d, 32 chunks of 16B per row; swizzle low 3 chunk bits)
#pragma unroll
  for (int rr = 0; rr < 8; ++rr) {
    int slot = rr * 256 + tid;
    int row = slot >> 5, sc = slot & 31;
    int c = (sc & 24) | ((sc & 7) ^ (row & 7));
    gld16(vp + row * 256 + c * 8, Vs + (rr * 256 + wave * 64) * 8);
  }
  __syncthreads();

  const int src_lo = ((quad & 1) << 5) + l15;   // same-l15 lane in quad 2*(quad&1)
  const int src_hi = src_lo + 16;
  const int hiSel = quad >> 1;

  for (int qblk = 0; qblk < 4; ++qblk) {
    const int qr0 = qblk * 64 + wave * 16;
    // Q as the B-operand: lane = q-row (n), quad*8 = d offset
    bf16x8 bq0 = *(const bf16x8*)(qp + (qr0 + l15) * DD + quad * 8);
    bf16x8 bq1 = *(const bf16x8*)(qp + (qr0 + l15) * DD + 32 + quad * 8);

    f32x4 sacc[16];
#pragma unroll
    for (int jt = 0; jt < 16; ++jt) sacc[jt] = (f32x4){0.f, 0.f, 0.f, 0.f};
#pragma unroll
    for (int jt = 0; jt < 16; ++jt) {
      const unsigned short* krow = Ks + (jt * 16 + l15) * 64;
      bf16x8 a0 = *(const bf16x8*)(krow + (quad ^ swl) * 8);
      bf16x8 a1 = *(const bf16x8*)(krow + ((4 + quad) ^ swl) * 8);
      sacc[jt] = __builtin_amdgcn_mfma_f32_16x16x32_bf16(a0, bq0, sacc[jt], 0, 0, 0);
      sacc[jt] = __builtin_amdgcn_mfma_f32_16x16x32_bf16(a1, bq1, sacc[jt], 0, 0, 0);
    }
    // sacc[jt][r] = S^T(k = jt*16+quad*4+r, q = qr0+l15), log2 domain.
    // exp2 + bias, pack to bf16 pairs, accumulate per-q sum in-lane.
    const float* bbp = biasm + ((size_t)(h * 256 + qr0 + l15)) * 256;
    float s = 0.f;
    uint2 pk[16];
#pragma unroll
    for (int jt = 0; jt < 16; ++jt) {
      float4 bv = *(const float4*)(bbp + jt * 16 + quad * 4);
      float e0 = fast_exp2(sacc[jt][0] + bv.x);
      float e1 = fast_exp2(sacc[jt][1] + bv.y);
      float e2 = fast_exp2(sacc[jt][2] + bv.z);
      float e3 = fast_exp2(sacc[jt][3] + bv.w);
      s += (e0 + e1) + (e2 + e3);
      union { float f; unsigned u; } u0, u1, u2, u3;
      u0.f = e0; u1.f = e1; u2.f = e2; u3.f = e3;
      pk[jt].x = ((u0.u + 0x8000u) >> 16) | ((u1.u + 0x8000u) & 0xffff0000u);
      pk[jt].y = ((u2.u + 0x8000u) >> 16) | ((u3.u + 0x8000u) & 0xffff0000u);
    }
    s += __shfl_xor(s, 16);
    s += __shfl_xor(s, 32);            // full k-sum for q = qr0+l15
    float rs = fast_rcp(s);

    // PV: assemble P A-frags via cross-quad shuffles, B = V rows from LDS
    f32x4 cacc[4];
#pragma unroll
    for (int nt = 0; nt < 4; ++nt) cacc[nt] = (f32x4){0.f, 0.f, 0.f, 0.f};
#pragma unroll
    for (int kk = 0; kk < 8; ++kk) {
      unsigned lex = __shfl((int)pk[2 * kk].x, src_lo);
      unsigned ley = __shfl((int)pk[2 * kk].y, src_lo);
      unsigned lox = __shfl((int)pk[2 * kk + 1].x, src_lo);
      unsigned loy = __shfl((int)pk[2 * kk + 1].y, src_lo);
      unsigned hex_ = __shfl((int)pk[2 * kk].x, src_hi);
      unsigned hey = __shfl((int)pk[2 * kk].y, src_hi);
      unsigned hox = __shfl((int)pk[2 * kk + 1].x, src_hi);
      unsigned hoy = __shfl((int)pk[2 * kk + 1].y, src_hi);
      union { unsigned u[4]; bf16x8 v; } af;
      af.u[0] = hiSel ? lox : lex;
      af.u[1] = hiSel ? loy : ley;
      af.u[2] = hiSel ? hox : hex_;
      af.u[3] = hiSel ? hoy : hey;
#pragma unroll
      for (int nt = 0; nt < 4; ++nt) {
        int c = kk * 4 + quad;
        int cp = (c & 24) | ((c & 7) ^ swl);
        bf16x8 b = *(const bf16x8*)(Vs + (nt * 16 + l15) * 256 + cp * 8);
        cacc[nt] = __builtin_amdgcn_mfma_f32_16x16x32_bf16(af.v, b, cacc[nt], 0, 0, 0);
      }
    }
    // epilogue: rows q = qr0+quad*4+r; fetch 1/sum from the lane that owns it
    float rsr[4];
#pragma unroll
    for (int r = 0; r < 4; ++r) rsr[r] = __shfl(rs, quad * 4 + r);
#pragma unroll
    for (int nt = 0; nt < 4; ++nt)
#pragma unroll
      for (int r = 0; r < 4; ++r)
        ctx[(size_t)(b_ * SS + qr0 + quad * 4 + r) * EE + h * DD + nt * 16 + l15] =
            f2bf(cacc[nt][r] * rsr[r]);
  }
}

// ---------------- out projection: ctx_bf16 @ out_w^T + out_b -> fp32 ----------------
__global__ __launch_bounds__(256) void out_gemm(const unsigned short* __restrict__ A,
                                                const unsigned short* __restrict__ Bw,
                                                const float* __restrict__ bias,
                                                float* __restrict__ out) {
  __shared__ unsigned short As[128 * 64];
  __shared__ unsigned short Bs[128 * 64];
  const int tid = threadIdx.x;
  const int wave = tid >> 6, lane = tid & 63;
  const int wm = wave & 1, wn = wave >> 1;
  const int l15 = lane & 15, quad = lane >> 4;
  const int row0 = blockIdx.x * 128;
  const int col0 = blockIdx.y * 128;
  f32x4 acc[4][4];
#pragma unroll
  for (int i = 0; i < 4; ++i)
#pragma unroll
    for (int j = 0; j < 4; ++j) acc[i][j] = (f32x4){0.f, 0.f, 0.f, 0.f};
  gemm_mainloop(A, Bw, As, Bs, row0, col0, EE, acc);
#pragma unroll
  for (int i = 0; i < 4; ++i) {
    const int m0 = row0 + wm * 64 + i * 16 + quad * 4;
#pragma unroll
    for (int j = 0; j < 4; ++j) {
      const int n = col0 + wn * 64 + j * 16 + l15;
      const float bv = bias[n];
#pragma unroll
      for (int r = 0; r < 4; ++r)
        out[(size_t)(m0 + r) * EE + n] = acc[i][j][r] + bv;
    }
  }
}

// ---------------- workspace layout (bytes) ----------------
#define WS_XCTX  ((size_t)0)
#define WS_QKVW  ((size_t)67108864)
#define WS_OUTW  ((size_t)73400320)
#define WS_BIAS  ((size_t)75497472)
#define WS_Q     ((size_t)79691776)
#define WS_K     ((size_t)146800640)
#define WS_VT    ((size_t)213909504)
// total required: 281,018,368 bytes

extern "C" void kernel_launch(void* const* d_in, const int* in_sizes, int n_in,
                              void* d_out, int out_size, void* d_ws, size_t ws_size,
                              hipStream_t stream) {
  (void)in_sizes; (void)n_in; (void)out_size; (void)ws_size;
  const float* x      = (const float*)d_in[0];
  const float* qkv_w  = (const float*)d_in[1];
  const float* qkv_b  = (const float*)d_in[2];
  const float* out_w  = (const float*)d_in[3];
  const float* out_b  = (const float*)d_in[4];
  const float* btab   = (const float*)d_in[5];
  const int*   ridx   = (const int*)d_in[6];
  float* out = (float*)d_out;
  char* ws = (char*)d_ws;

  unsigned short* xctx  = (unsigned short*)(ws + WS_XCTX);
  unsigned short* qkvwb = (unsigned short*)(ws + WS_QKVW);
  unsigned short* outwb = (unsigned short*)(ws + WS_OUTW);
  float*          biasm = (float*)(ws + WS_BIAS);
  unsigned short* q     = (unsigned short*)(ws + WS_Q);
  unsigned short* k     = (unsigned short*)(ws + WS_K);
  unsigned short* vt    = (unsigned short*)(ws + WS_VT);

  prep_kernel<<<8192, 256, 0, stream>>>((const float4*)x, (const float4*)qkv_w,
                                        (const float4*)out_w, btab, ridx,
                                        (ushort4*)xctx, (ushort4*)qkvwb,
                                        (ushort4*)outwb, biasm);
  qkv_gemm<<<dim3(MM / 128, (3 * EE) / 128), 256, 0, stream>>>(xctx, qkvwb, qkv_b,
                                                               q, k, vt);
  attn_kernel<<<BB * HH, 256, 0, stream>>>(q, k, vt, biasm, xctx);
  out_gemm<<<dim3(MM / 128, EE / 128), 256, 0, stream>>>(xctx, outwb, out_b, out);
}